// Round 18
// baseline (137.444 us; speedup 1.0000x reference)
//
#include <hip/hip_runtime.h>
#include <hip/hip_bf16.h>

#define DIM 64
#define NRELS 8
#define NBASES 4
#define KTOT 576          // 8*64 relation cols + 64 self cols
#define KCH 18            // KTOT / 32 MFMA k-chunks
#define LDSPAD 584        // tile row stride in ushorts (1168B; skews 16B slots per row)
#define BKT_SHIFT 7
#define BKT_NODES 128
#define MAXBKT 1024
#define CAP 4096
#define P3_CHUNK 4096

typedef __attribute__((ext_vector_type(8))) short short8;
typedef __attribute__((ext_vector_type(4))) float f32x4;

__device__ inline unsigned short f2bf(float f) {
    union { float f; unsigned int u; } v; v.f = f;
    unsigned int u = v.u;
    unsigned int r = u + 0x7FFFu + ((u >> 16) & 1u);
    return (unsigned short)(r >> 16);
}
__device__ inline float bflo(unsigned u) {  // f32 from low bf16 of dword (1 shl)
    union { unsigned u; float f; } v; v.u = u << 16;
    return v.f;
}
__device__ inline float bfhi(unsigned u) {  // f32 from high bf16 of dword (1 and)
    union { unsigned u; float f; } v; v.u = u & 0xFFFF0000u;
    return v.f;
}
// pack two f32 -> (bf16(lo) | bf16(hi)<<16) in one HW instruction (RNE)
__device__ inline unsigned cvtpk(float lo, float hi) {
    unsigned r;
    asm("v_cvt_pk_bf16_f32 %0, %1, %2" : "=v"(r) : "v"(lo), "v"(hi));
    return r;
}

// Combined prep: cast emb f32->bf16 (NN*8 octets), pack Wcat for both layers into
// MFMA B-fragment order, zero-init bktpos.
__global__ __launch_bounds__(256) void prep_kernel(const float* __restrict__ emb,
                                                   unsigned short* __restrict__ embbf, int n8,
                                                   const float* __restrict__ bases1,
                                                   const float* __restrict__ coef1,
                                                   const float* __restrict__ wself1,
                                                   unsigned short* __restrict__ Wpk1,
                                                   const float* __restrict__ bases2,
                                                   const float* __restrict__ coef2,
                                                   const float* __restrict__ wself2,
                                                   unsigned short* __restrict__ Wpk2,
                                                   int* __restrict__ bktpos) {
    int idx = blockIdx.x * blockDim.x + threadIdx.x;
    if (idx < MAXBKT) bktpos[idx] = 0;
    if (idx < n8) {
        const float4* p = (const float4*)(emb + (size_t)idx * 8);
        float4 a = p[0], b = p[1];
        uint4 v;
        v.x = cvtpk(a.x, a.y);
        v.y = cvtpk(a.z, a.w);
        v.z = cvtpk(b.x, b.y);
        v.w = cvtpk(b.z, b.w);
        *(uint4*)(embbf + (size_t)idx * 8) = v;
    }
    if (idx < 2 * KTOT * DIM) {
        int set = (idx >= KTOT * DIM);
        const float* bases = set ? bases2 : bases1;
        const float* coef  = set ? coef2 : coef1;
        const float* wself = set ? wself2 : wself1;
        unsigned short* Wpk = set ? Wpk2 : Wpk1;
        int id2 = idx - set * KTOT * DIM;
        int k = id2 >> 6;          // 0..575
        int j = id2 & 63;
        float v;
        if (k < 512) {
            int rel = k >> 6, i = k & 63;
            v = 0.f;
#pragma unroll
            for (int b = 0; b < NBASES; ++b)
                v += coef[rel * NBASES + b] * bases[((size_t)b * DIM + i) * DIM + j];
        } else {
            v = wself[(k - 512) * DIM + j];
        }
        int ch = k >> 5, within = k & 31, lhi = within >> 3, e = within & 7;
        int jt = j >> 4, lane = lhi * 16 + (j & 15);
        Wpk[(size_t)(((ch * 4 + jt) * 64 + lane) * 8 + e)] = f2bf(v);
    }
}

// Partition edges into fixed-stride buckets, packed src | et<<17 | dstlow<<20.
__global__ __launch_bounds__(256) void partition2(const int* __restrict__ src,
                                                  const int* __restrict__ dst,
                                                  const int* __restrict__ et,
                                                  int* __restrict__ bktpos,
                                                  unsigned* __restrict__ perm_tmp,
                                                  int n_edges, int nbkt) {
    __shared__ int h[MAXBKT];
    __shared__ int base[MAXBKT];
    int t = threadIdx.x;
    for (int i = t; i < nbkt; i += 256) h[i] = 0;
    __syncthreads();
    int e0 = blockIdx.x * P3_CHUNK;
#pragma unroll
    for (int k = 0; k < P3_CHUNK / 256; ++k) {
        int e = e0 + k * 256 + t;
        if (e < n_edges) atomicAdd(&h[dst[e] >> BKT_SHIFT], 1);
    }
    __syncthreads();
    for (int i = t; i < nbkt; i += 256) {
        int c = h[i];
        base[i] = c ? atomicAdd(&bktpos[i], c) : 0;
        h[i] = 0;
    }
    __syncthreads();
#pragma unroll
    for (int k = 0; k < P3_CHUNK / 256; ++k) {
        int e = e0 + k * 256 + t;
        if (e < n_edges) {
            int d = dst[e];
            int bk = d >> BKT_SHIFT;
            int rk = atomicAdd(&h[bk], 1);
            perm_tmp[(size_t)bk * CAP + base[bk] + rk] =
                (unsigned)src[e] | ((unsigned)et[e] << 17) | ((unsigned)(d & (BKT_NODES - 1)) << 20);
        }
    }
}

// One block per bucket: sort by 10-bit key (dstlow*8 + rel). Emits per-(dst,rel)
// segment starts seg[node*8+r], per-dst end dend[node], and perm = src*128
// (pre-scaled ROW BYTE OFFSET into hbf — saves 64-bit addr math in the hot loop).
__global__ __launch_bounds__(256) void bucket_csr3(const unsigned* __restrict__ perm_tmp,
                                                   const int* __restrict__ bktpos,
                                                   unsigned* __restrict__ perm,
                                                   int* __restrict__ seg, int* __restrict__ dend,
                                                   int n_nodes) {
    __shared__ int h[1024];
    __shared__ int ex[1024];
    __shared__ int wtot[4];
    const int t = threadIdx.x;
    const int b = blockIdx.x;
    const int cnt = bktpos[b];
    const size_t bb = (size_t)b * CAP;
    for (int i = t; i < 1024; i += 256) h[i] = 0;
    __syncthreads();
    for (int i = t; i < cnt; i += 256) atomicAdd(&h[(perm_tmp[bb + i] >> 17) & 1023], 1);
    __syncthreads();
    int v0 = h[4 * t], v1 = h[4 * t + 1], v2 = h[4 * t + 2], v3 = h[4 * t + 3];
    int s = v0 + v1 + v2 + v3;
    int lane = t & 63, w = t >> 6;
    int x = s;
#pragma unroll
    for (int ofs = 1; ofs < 64; ofs <<= 1) {
        int y = __shfl_up(x, ofs);
        if (lane >= ofs) x += y;
    }
    if (lane == 63) wtot[w] = x;
    __syncthreads();
    int woff = 0;
    for (int k = 0; k < w; ++k) woff += wtot[k];
    int run = woff + x - s;
    ex[4 * t] = run; run += v0;
    ex[4 * t + 1] = run; run += v1;
    ex[4 * t + 2] = run; run += v2;
    ex[4 * t + 3] = run;
    __syncthreads();
    for (int k = t; k < 1024; k += 256) {
        int node = b * BKT_NODES + (k >> 3);
        if (node < n_nodes) {
            seg[(size_t)node * 8 + (k & 7)] = b * CAP + ex[k];
            if ((k & 7) == 7) dend[node] = b * CAP + ((k == 1023) ? cnt : ex[k + 1]);
        }
    }
    __syncthreads();
    for (int i = t; i < cnt; i += 256) {
        unsigned rc = perm_tmp[bb + i];
        int p = atomicAdd(&ex[(rc >> 17) & 1023], 1);
        perm[bb + p] = (rc & 0x1FFFFu) << 7;  // src * 128 bytes
    }
}

// Fused aggregate + project: 16 dst per block (4 waves x 4 dst).
// Per dst: 16 lanes = 2 rel-slots x 8 col-octets. Slot 0 owns rels {0,2,4,6},
// slot 1 owns {1,3,5,7}; edge loop 2-deep unrolled UNGUARDED + 1 tail.
// perm entries are pre-scaled byte offsets; plds holds 32/dst so the global
// fallback is ~never taken (P[deg>32] ~ 1e-7). Pack via v_cvt_pk_bf16_f32;
// A-tile [16][576] bf16 in LDS, K=576 MFMA vs packed Wcat.
template <bool OUT_F32>
__global__ __launch_bounds__(256) void rgcn_fused(const unsigned* __restrict__ perm,
                                                  const int* __restrict__ seg,
                                                  const int* __restrict__ dend,
                                                  const unsigned short* __restrict__ hbf,
                                                  const unsigned short* __restrict__ Wpk,
                                                  const float* __restrict__ bias,
                                                  float* __restrict__ out32,
                                                  unsigned short* __restrict__ outbf,
                                                  int n_nodes) {
    __shared__ unsigned short tile[16 * LDSPAD];
    __shared__ unsigned plds[16][32];   // prefetched pre-scaled perm entries per local dst
    const int lane = threadIdx.x & 63;
    const int wave = threadIdx.x >> 6;
    const int d0 = blockIdx.x * 16;
    const int di = lane >> 4;          // dst within wave (0..3)
    const int ld = wave * 4 + di;      // local dst row (0..15)
    const int d = d0 + ld;
    const int slot = (lane >> 3) & 1;  // rel parity slot
    const int s = lane & 7;            // col octet
    const int sb = s * 16;             // byte offset within row
    const int il = lane & 15;
    const bool valid = d < n_nodes;
    const int dc = valid ? d : 0;
    const char* hb = (const char*)hbf;

    // per-lane segment bounds: il<8 -> seg[d*8+il], il==8 -> dend[d]
    int rbv = 0;
    if (valid) rbv = (il < 8) ? seg[(size_t)dc * 8 + il] : dend[dc];
    const int beg = __shfl(rbv, (di << 4));       // converged: safe
    const int dv  = __shfl(rbv, (di << 4) + 8);

    // prefetch up to 32 perm entries for this dst into LDS (divergence-safe reads later)
    unsigned p0 = 0u, p1 = 0u;
    if (valid && beg + il < dv) p0 = perm[beg + il];
    if (valid && beg + 16 + il < dv) p1 = perm[beg + 16 + il];
    plds[ld][il] = p0;
    plds[ld][il + 16] = p1;

    // self row -> tile cols 512..575 (slot-1 lanes, direct bf16 copy)
    if (slot == 1) {
        uint4 v = make_uint4(0u, 0u, 0u, 0u);
        if (valid) v = *(const uint4*)(hbf + (size_t)dc * DIM + s * 8);
        *(uint4*)&tile[ld * LDSPAD + 512 + s * 8] = v;
    }

#pragma unroll
    for (int rp = 0; rp < 4; ++rp) {
        const int rel = rp * 2 + slot;  // slot 0: 0,2,4,6; slot 1: 1,3,5,7
        int rb = __shfl(rbv, (di << 4) + rel);                       // converged: safe
        int re = __shfl(rbv, (di << 4) + ((rel < 7) ? rel + 1 : 8)); // rel7 end = dend
        float a0 = 0.f, a1 = 0.f, a2 = 0.f, a3 = 0.f, a4 = 0.f, a5 = 0.f, a6 = 0.f, a7 = 0.f;
        int e = rb;
        for (; e + 1 < re; e += 2) {
            int r0 = e - beg, r1 = r0 + 1;
            unsigned rc0 = (r0 < 32) ? plds[ld][r0] : perm[e];      // LDS: divergence-safe
            unsigned rc1 = (r1 < 32) ? plds[ld][r1] : perm[e + 1];
            uint4 v = *(const uint4*)(hb + (rc0 + sb));
            uint4 u = *(const uint4*)(hb + (rc1 + sb));
            a0 += bflo(v.x); a1 += bfhi(v.x);
            a2 += bflo(v.y); a3 += bfhi(v.y);
            a4 += bflo(v.z); a5 += bfhi(v.z);
            a6 += bflo(v.w); a7 += bfhi(v.w);
            a0 += bflo(u.x); a1 += bfhi(u.x);
            a2 += bflo(u.y); a3 += bfhi(u.y);
            a4 += bflo(u.z); a5 += bfhi(u.z);
            a6 += bflo(u.w); a7 += bfhi(u.w);
        }
        if (e < re) {
            int r0 = e - beg;
            unsigned rc = (r0 < 32) ? plds[ld][r0] : perm[e];
            uint4 v = *(const uint4*)(hb + (rc + sb));
            a0 += bflo(v.x); a1 += bfhi(v.x);
            a2 += bflo(v.y); a3 += bfhi(v.y);
            a4 += bflo(v.z); a5 += bfhi(v.z);
            a6 += bflo(v.w); a7 += bfhi(v.w);
        }
        // a1,a3,a5,a7 hold the high-bf16 sums (bfhi preserves value); cvtpk packs (lo,hi)
        uint4 v;
        v.x = cvtpk(a0, a1);
        v.y = cvtpk(a2, a3);
        v.z = cvtpk(a4, a5);
        v.w = cvtpk(a6, a7);
        *(uint4*)&tile[ld * LDSPAD + rel * 64 + s * 8] = v;
    }
    __syncthreads();

    // MFMA phase: wave = output col quadrant jt; A rows = 16 dst, K = 576.
    const int lrow = lane & 15;
    const int lhi = lane >> 4;
    f32x4 c = {0.f, 0.f, 0.f, 0.f};
#pragma unroll
    for (int ch = 0; ch < KCH; ++ch) {
        short8 af = *(const short8*)&tile[lrow * LDSPAD + ch * 32 + lhi * 8];
        short8 bfr = *(const short8*)(Wpk + (size_t)(((ch * 4 + wave) * 64 + lane) * 8));
        c = __builtin_amdgcn_mfma_f32_16x16x32_bf16(af, bfr, c, 0, 0, 0);
    }
    const int col = wave * 16 + lrow;
    const float bj = bias[col];
#pragma unroll
    for (int reg = 0; reg < 4; ++reg) {
        int rr = lhi * 4 + reg;
        int dd = d0 + rr;
        if (dd < n_nodes) {
            float val = c[reg] + bj;
            if (OUT_F32) out32[(size_t)dd * DIM + col] = val;
            else outbf[(size_t)dd * DIM + col] = f2bf(val);
        }
    }
}

extern "C" void kernel_launch(void* const* d_in, const int* in_sizes, int n_in,
                              void* d_out, int out_size, void* d_ws, size_t ws_size,
                              hipStream_t stream) {
    const int* src = (const int*)d_in[0];
    const int* dst = (const int*)d_in[1];
    const int* et  = (const int*)d_in[2];
    const float* emb    = (const float*)d_in[3];
    const float* bases1 = (const float*)d_in[4];
    const float* coef1  = (const float*)d_in[5];
    const float* wself1 = (const float*)d_in[6];
    const float* bias1  = (const float*)d_in[7];
    const float* bases2 = (const float*)d_in[8];
    const float* coef2  = (const float*)d_in[9];
    const float* wself2 = (const float*)d_in[10];
    const float* bias2  = (const float*)d_in[11];
    float* out = (float*)d_out;

    const int NE = in_sizes[0];
    const int NN = in_sizes[3] / DIM;
    const int NBKT = (NN + BKT_NODES - 1) / BKT_NODES;  // 782

    // Workspace: Wpk1|Wpk2|embbf|h1bf|bktpos|seg|dend|perm_tmp|perm  (~56 MB)
    unsigned short* Wpk1 = (unsigned short*)d_ws;
    unsigned short* Wpk2 = Wpk1 + (size_t)KCH * 4 * 64 * 8;
    unsigned short* embbf = Wpk2 + (size_t)KCH * 4 * 64 * 8;
    unsigned short* h1bf = embbf + (size_t)NN * DIM;
    int* bktpos = (int*)(h1bf + (size_t)NN * DIM);
    int* seg = bktpos + MAXBKT;
    int* dend = seg + (size_t)NN * 8 + 64;
    unsigned* perm_tmp = (unsigned*)(dend + NN + 64);
    unsigned* perm = perm_tmp + (size_t)NBKT * CAP;

    const int prep_threads = NN * 8;  // covers cast (NN*8), wpk (73728), bktpos (1024)
    prep_kernel<<<(prep_threads + 255) / 256, 256, 0, stream>>>(
        emb, embbf, NN * 8, bases1, coef1, wself1, Wpk1, bases2, coef2, wself2, Wpk2, bktpos);

    partition2<<<(NE + P3_CHUNK - 1) / P3_CHUNK, 256, 0, stream>>>(src, dst, et, bktpos,
                                                                   perm_tmp, NE, NBKT);
    bucket_csr3<<<NBKT, 256, 0, stream>>>(perm_tmp, bktpos, perm, seg, dend, NN);

    const int fused_blocks = (NN + 15) / 16;

    // Layer 1: h1 (bf16) = RGCN(embbf)
    rgcn_fused<false><<<fused_blocks, 256, 0, stream>>>(perm, seg, dend, embbf, Wpk1, bias1,
                                                        nullptr, h1bf, NN);
    // Layer 2: out (f32) = RGCN(h1bf)
    rgcn_fused<true><<<fused_blocks, 256, 0, stream>>>(perm, seg, dend, h1bf, Wpk2, bias2,
                                                       out, nullptr, NN);
}

// Round 19
// 135.889 us; speedup vs baseline: 1.0114x; 1.0114x over previous
//
#include <hip/hip_runtime.h>
#include <hip/hip_bf16.h>

#define DIM 64
#define NRELS 8
#define NBASES 4
#define KTOT 576          // 8*64 relation cols + 64 self cols
#define KCH 18            // KTOT / 32 MFMA k-chunks
#define LDSPAD 584        // tile row stride in ushorts (1168B; skews 16B slots per row)
#define BKT_SHIFT 7
#define BKT_NODES 128
#define MAXBKT 1024
#define CAP 4096
#define P3_CHUNK 4096

typedef __attribute__((ext_vector_type(8))) short short8;
typedef __attribute__((ext_vector_type(4))) float f32x4;

__device__ inline unsigned short f2bf(float f) {
    union { float f; unsigned int u; } v; v.f = f;
    unsigned int u = v.u;
    unsigned int r = u + 0x7FFFu + ((u >> 16) & 1u);
    return (unsigned short)(r >> 16);
}
__device__ inline float bflo(unsigned u) {  // f32 from low bf16 of dword (1 shl)
    union { unsigned u; float f; } v; v.u = u << 16;
    return v.f;
}
__device__ inline float bfhi(unsigned u) {  // f32 from high bf16 of dword (1 and)
    union { unsigned u; float f; } v; v.u = u & 0xFFFF0000u;
    return v.f;
}
// pack two f32 -> (bf16(lo) | bf16(hi)<<16) in one HW instruction (RNE)
__device__ inline unsigned cvtpk(float lo, float hi) {
    unsigned r;
    asm("v_cvt_pk_bf16_f32 %0, %1, %2" : "=v"(r) : "v"(lo), "v"(hi));
    return r;
}

// Combined prep: cast emb f32->bf16 (NN*8 octets), pack Wcat for both layers into
// MFMA B-fragment order, zero-init bktpos.
__global__ __launch_bounds__(256) void prep_kernel(const float* __restrict__ emb,
                                                   unsigned short* __restrict__ embbf, int n8,
                                                   const float* __restrict__ bases1,
                                                   const float* __restrict__ coef1,
                                                   const float* __restrict__ wself1,
                                                   unsigned short* __restrict__ Wpk1,
                                                   const float* __restrict__ bases2,
                                                   const float* __restrict__ coef2,
                                                   const float* __restrict__ wself2,
                                                   unsigned short* __restrict__ Wpk2,
                                                   int* __restrict__ bktpos) {
    int idx = blockIdx.x * blockDim.x + threadIdx.x;
    if (idx < MAXBKT) bktpos[idx] = 0;
    if (idx < n8) {
        const float4* p = (const float4*)(emb + (size_t)idx * 8);
        float4 a = p[0], b = p[1];
        uint4 v;
        v.x = cvtpk(a.x, a.y);
        v.y = cvtpk(a.z, a.w);
        v.z = cvtpk(b.x, b.y);
        v.w = cvtpk(b.z, b.w);
        *(uint4*)(embbf + (size_t)idx * 8) = v;
    }
    if (idx < 2 * KTOT * DIM) {
        int set = (idx >= KTOT * DIM);
        const float* bases = set ? bases2 : bases1;
        const float* coef  = set ? coef2 : coef1;
        const float* wself = set ? wself2 : wself1;
        unsigned short* Wpk = set ? Wpk2 : Wpk1;
        int id2 = idx - set * KTOT * DIM;
        int k = id2 >> 6;          // 0..575
        int j = id2 & 63;
        float v;
        if (k < 512) {
            int rel = k >> 6, i = k & 63;
            v = 0.f;
#pragma unroll
            for (int b = 0; b < NBASES; ++b)
                v += coef[rel * NBASES + b] * bases[((size_t)b * DIM + i) * DIM + j];
        } else {
            v = wself[(k - 512) * DIM + j];
        }
        int ch = k >> 5, within = k & 31, lhi = within >> 3, e = within & 7;
        int jt = j >> 4, lane = lhi * 16 + (j & 15);
        Wpk[(size_t)(((ch * 4 + jt) * 64 + lane) * 8 + e)] = f2bf(v);
    }
}

// Partition edges into fixed-stride buckets, packed src | et<<17 | dstlow<<20.
__global__ __launch_bounds__(256) void partition2(const int* __restrict__ src,
                                                  const int* __restrict__ dst,
                                                  const int* __restrict__ et,
                                                  int* __restrict__ bktpos,
                                                  unsigned* __restrict__ perm_tmp,
                                                  int n_edges, int nbkt) {
    __shared__ int h[MAXBKT];
    __shared__ int base[MAXBKT];
    int t = threadIdx.x;
    for (int i = t; i < nbkt; i += 256) h[i] = 0;
    __syncthreads();
    int e0 = blockIdx.x * P3_CHUNK;
#pragma unroll
    for (int k = 0; k < P3_CHUNK / 256; ++k) {
        int e = e0 + k * 256 + t;
        if (e < n_edges) atomicAdd(&h[dst[e] >> BKT_SHIFT], 1);
    }
    __syncthreads();
    for (int i = t; i < nbkt; i += 256) {
        int c = h[i];
        base[i] = c ? atomicAdd(&bktpos[i], c) : 0;
        h[i] = 0;
    }
    __syncthreads();
#pragma unroll
    for (int k = 0; k < P3_CHUNK / 256; ++k) {
        int e = e0 + k * 256 + t;
        if (e < n_edges) {
            int d = dst[e];
            int bk = d >> BKT_SHIFT;
            int rk = atomicAdd(&h[bk], 1);
            perm_tmp[(size_t)bk * CAP + base[bk] + rk] =
                (unsigned)src[e] | ((unsigned)et[e] << 17) | ((unsigned)(d & (BKT_NODES - 1)) << 20);
        }
    }
}

// One block per bucket: sort by 10-bit key (dstlow*8 + rel). Emits per-(dst,rel)
// segment starts seg[node*8+r], per-dst end dend[node], and perm = src (17 bits).
__global__ __launch_bounds__(256) void bucket_csr3(const unsigned* __restrict__ perm_tmp,
                                                   const int* __restrict__ bktpos,
                                                   unsigned* __restrict__ perm,
                                                   int* __restrict__ seg, int* __restrict__ dend,
                                                   int n_nodes) {
    __shared__ int h[1024];
    __shared__ int ex[1024];
    __shared__ int wtot[4];
    const int t = threadIdx.x;
    const int b = blockIdx.x;
    const int cnt = bktpos[b];
    const size_t bb = (size_t)b * CAP;
    for (int i = t; i < 1024; i += 256) h[i] = 0;
    __syncthreads();
    for (int i = t; i < cnt; i += 256) atomicAdd(&h[(perm_tmp[bb + i] >> 17) & 1023], 1);
    __syncthreads();
    int v0 = h[4 * t], v1 = h[4 * t + 1], v2 = h[4 * t + 2], v3 = h[4 * t + 3];
    int s = v0 + v1 + v2 + v3;
    int lane = t & 63, w = t >> 6;
    int x = s;
#pragma unroll
    for (int ofs = 1; ofs < 64; ofs <<= 1) {
        int y = __shfl_up(x, ofs);
        if (lane >= ofs) x += y;
    }
    if (lane == 63) wtot[w] = x;
    __syncthreads();
    int woff = 0;
    for (int k = 0; k < w; ++k) woff += wtot[k];
    int run = woff + x - s;
    ex[4 * t] = run; run += v0;
    ex[4 * t + 1] = run; run += v1;
    ex[4 * t + 2] = run; run += v2;
    ex[4 * t + 3] = run;
    __syncthreads();
    for (int k = t; k < 1024; k += 256) {
        int node = b * BKT_NODES + (k >> 3);
        if (node < n_nodes) {
            seg[(size_t)node * 8 + (k & 7)] = b * CAP + ex[k];
            if ((k & 7) == 7) dend[node] = b * CAP + ((k == 1023) ? cnt : ex[k + 1]);
        }
    }
    __syncthreads();
    for (int i = t; i < cnt; i += 256) {
        unsigned rc = perm_tmp[bb + i];
        int p = atomicAdd(&ex[(rc >> 17) & 1023], 1);
        perm[bb + p] = rc & 0x1FFFFu;  // src only
    }
}

// Fused aggregate + project: 16 dst per block (4 waves x 4 dst).
// Per dst: 16 lanes = 2 rel-slots x 8 col-octets. Slot 0 owns rels {0,2,4,6},
// slot 1 owns {1,3,5,7}; edge loop 2-deep unrolled UNGUARDED (two unconditional
// loads in one straight-line block — masked unroll-4 regressed, r16) + 1 tail.
// Pack via v_cvt_pk_bf16_f32; A-tile [16][576] bf16 in LDS, K=576 MFMA vs Wcat.
template <bool OUT_F32>
__global__ __launch_bounds__(256) void rgcn_fused(const unsigned* __restrict__ perm,
                                                  const int* __restrict__ seg,
                                                  const int* __restrict__ dend,
                                                  const unsigned short* __restrict__ hbf,
                                                  const unsigned short* __restrict__ Wpk,
                                                  const float* __restrict__ bias,
                                                  float* __restrict__ out32,
                                                  unsigned short* __restrict__ outbf,
                                                  int n_nodes) {
    __shared__ unsigned short tile[16 * LDSPAD];
    __shared__ unsigned plds[16][16];   // prefetched perm entries per local dst
    const int lane = threadIdx.x & 63;
    const int wave = threadIdx.x >> 6;
    const int d0 = blockIdx.x * 16;
    const int di = lane >> 4;          // dst within wave (0..3)
    const int ld = wave * 4 + di;      // local dst row (0..15)
    const int d = d0 + ld;
    const int slot = (lane >> 3) & 1;  // rel parity slot
    const int s = lane & 7;            // col octet
    const int il = lane & 15;
    const bool valid = d < n_nodes;
    const int dc = valid ? d : 0;

    // per-lane segment bounds: il<8 -> seg[d*8+il], il==8 -> dend[d]
    int rbv = 0;
    if (valid) rbv = (il < 8) ? seg[(size_t)dc * 8 + il] : dend[dc];
    const int beg = __shfl(rbv, (di << 4));       // converged: safe
    const int dv  = __shfl(rbv, (di << 4) + 8);

    // prefetch up to 16 perm entries for this dst into LDS (divergence-safe reads later)
    unsigned pvv = 0u;
    if (valid && beg + il < dv) pvv = perm[beg + il];
    plds[ld][il] = pvv;

    // self row -> tile cols 512..575 (slot-1 lanes, direct bf16 copy)
    if (slot == 1) {
        uint4 v = make_uint4(0u, 0u, 0u, 0u);
        if (valid) v = *(const uint4*)(hbf + (size_t)dc * DIM + s * 8);
        *(uint4*)&tile[ld * LDSPAD + 512 + s * 8] = v;
    }

#pragma unroll
    for (int rp = 0; rp < 4; ++rp) {
        const int rel = rp * 2 + slot;  // slot 0: 0,2,4,6; slot 1: 1,3,5,7
        int rb = __shfl(rbv, (di << 4) + rel);                       // converged: safe
        int re = __shfl(rbv, (di << 4) + ((rel < 7) ? rel + 1 : 8)); // rel7 end = dend
        float a0 = 0.f, a1 = 0.f, a2 = 0.f, a3 = 0.f, a4 = 0.f, a5 = 0.f, a6 = 0.f, a7 = 0.f;
        int e = rb;
        for (; e + 1 < re; e += 2) {
            int r0 = e - beg, r1 = r0 + 1;
            unsigned rc0 = (r0 < 16) ? plds[ld][r0] : perm[e];      // LDS: divergence-safe
            unsigned rc1 = (r1 < 16) ? plds[ld][r1] : perm[e + 1];
            uint4 v = *(const uint4*)(hbf + (size_t)rc0 * DIM + s * 8);
            uint4 u = *(const uint4*)(hbf + (size_t)rc1 * DIM + s * 8);
            a0 += bflo(v.x); a1 += bfhi(v.x);
            a2 += bflo(v.y); a3 += bfhi(v.y);
            a4 += bflo(v.z); a5 += bfhi(v.z);
            a6 += bflo(v.w); a7 += bfhi(v.w);
            a0 += bflo(u.x); a1 += bfhi(u.x);
            a2 += bflo(u.y); a3 += bfhi(u.y);
            a4 += bflo(u.z); a5 += bfhi(u.z);
            a6 += bflo(u.w); a7 += bfhi(u.w);
        }
        if (e < re) {
            int r0 = e - beg;
            unsigned rc = (r0 < 16) ? plds[ld][r0] : perm[e];
            uint4 v = *(const uint4*)(hbf + (size_t)rc * DIM + s * 8);
            a0 += bflo(v.x); a1 += bfhi(v.x);
            a2 += bflo(v.y); a3 += bfhi(v.y);
            a4 += bflo(v.z); a5 += bfhi(v.z);
            a6 += bflo(v.w); a7 += bfhi(v.w);
        }
        // a1,a3,a5,a7 hold the high-bf16 sums (bfhi preserves value); cvtpk packs (lo,hi)
        uint4 v;
        v.x = cvtpk(a0, a1);
        v.y = cvtpk(a2, a3);
        v.z = cvtpk(a4, a5);
        v.w = cvtpk(a6, a7);
        *(uint4*)&tile[ld * LDSPAD + rel * 64 + s * 8] = v;
    }
    __syncthreads();

    // MFMA phase: wave = output col quadrant jt; A rows = 16 dst, K = 576.
    const int lrow = lane & 15;
    const int lhi = lane >> 4;
    f32x4 c = {0.f, 0.f, 0.f, 0.f};
#pragma unroll
    for (int ch = 0; ch < KCH; ++ch) {
        short8 af = *(const short8*)&tile[lrow * LDSPAD + ch * 32 + lhi * 8];
        short8 bfr = *(const short8*)(Wpk + (size_t)(((ch * 4 + wave) * 64 + lane) * 8));
        c = __builtin_amdgcn_mfma_f32_16x16x32_bf16(af, bfr, c, 0, 0, 0);
    }
    const int col = wave * 16 + lrow;
    const float bj = bias[col];
#pragma unroll
    for (int reg = 0; reg < 4; ++reg) {
        int rr = lhi * 4 + reg;
        int dd = d0 + rr;
        if (dd < n_nodes) {
            float val = c[reg] + bj;
            if (OUT_F32) out32[(size_t)dd * DIM + col] = val;
            else outbf[(size_t)dd * DIM + col] = f2bf(val);
        }
    }
}

extern "C" void kernel_launch(void* const* d_in, const int* in_sizes, int n_in,
                              void* d_out, int out_size, void* d_ws, size_t ws_size,
                              hipStream_t stream) {
    const int* src = (const int*)d_in[0];
    const int* dst = (const int*)d_in[1];
    const int* et  = (const int*)d_in[2];
    const float* emb    = (const float*)d_in[3];
    const float* bases1 = (const float*)d_in[4];
    const float* coef1  = (const float*)d_in[5];
    const float* wself1 = (const float*)d_in[6];
    const float* bias1  = (const float*)d_in[7];
    const float* bases2 = (const float*)d_in[8];
    const float* coef2  = (const float*)d_in[9];
    const float* wself2 = (const float*)d_in[10];
    const float* bias2  = (const float*)d_in[11];
    float* out = (float*)d_out;

    const int NE = in_sizes[0];
    const int NN = in_sizes[3] / DIM;
    const int NBKT = (NN + BKT_NODES - 1) / BKT_NODES;  // 782

    // Workspace: Wpk1|Wpk2|embbf|h1bf|bktpos|seg|dend|perm_tmp|perm  (~56 MB)
    unsigned short* Wpk1 = (unsigned short*)d_ws;
    unsigned short* Wpk2 = Wpk1 + (size_t)KCH * 4 * 64 * 8;
    unsigned short* embbf = Wpk2 + (size_t)KCH * 4 * 64 * 8;
    unsigned short* h1bf = embbf + (size_t)NN * DIM;
    int* bktpos = (int*)(h1bf + (size_t)NN * DIM);
    int* seg = bktpos + MAXBKT;
    int* dend = seg + (size_t)NN * 8 + 64;
    unsigned* perm_tmp = (unsigned*)(dend + NN + 64);
    unsigned* perm = perm_tmp + (size_t)NBKT * CAP;

    const int prep_threads = NN * 8;  // covers cast (NN*8), wpk (73728), bktpos (1024)
    prep_kernel<<<(prep_threads + 255) / 256, 256, 0, stream>>>(
        emb, embbf, NN * 8, bases1, coef1, wself1, Wpk1, bases2, coef2, wself2, Wpk2, bktpos);

    partition2<<<(NE + P3_CHUNK - 1) / P3_CHUNK, 256, 0, stream>>>(src, dst, et, bktpos,
                                                                   perm_tmp, NE, NBKT);
    bucket_csr3<<<NBKT, 256, 0, stream>>>(perm_tmp, bktpos, perm, seg, dend, NN);

    const int fused_blocks = (NN + 15) / 16;

    // Layer 1: h1 (bf16) = RGCN(embbf)
    rgcn_fused<false><<<fused_blocks, 256, 0, stream>>>(perm, seg, dend, embbf, Wpk1, bias1,
                                                        nullptr, h1bf, NN);
    // Layer 2: out (f32) = RGCN(h1bf)
    rgcn_fused<true><<<fused_blocks, 256, 0, stream>>>(perm, seg, dend, h1bf, Wpk2, bias2,
                                                       out, nullptr, NN);
}